// Round 3
// baseline (1266.451 us; speedup 1.0000x reference)
//
#include <hip/hip_runtime.h>
#include <stdint.h>

// CrossAttention. Inputs may be fp32 (per reference) or bf16 (per test label)
// — a detect kernel inspects W1's bit patterns and sets a ws flag; all
// conversion kernels and the final output writer branch on it. The compute
// pipeline itself is all-bf16: m97-style 128x128 MFMA GEMM (verified layout),
// d_out doubles as the two 32 MiB bf16 ping/pong activation buffers.
//   h = relu-MLP(x) [4 layers], q = h@Wq+bq, k = y@Wk+bk,
//   per batch: vt_b = (y_b@Wv+bv)^T, S_b = q_b k_b^T/32, softmax,
//   out_b = S_b@v_b -> OUTS (ws), final writer OUTS -> d_out (fp32 or bf16).

typedef __attribute__((ext_vector_type(8))) short bf16x8;
typedef __attribute__((ext_vector_type(4))) float f32x4;
typedef __attribute__((ext_vector_type(8))) unsigned short u16x8;

__device__ __forceinline__ float bf2f(unsigned short u) {
    return __uint_as_float(((unsigned int)u) << 16);
}
__device__ __forceinline__ unsigned short f2bf(float f) {
    unsigned int u = __float_as_uint(f);
    unsigned int r = (u + 0x7fffu + ((u >> 16) & 1u)) >> 16;
    return (unsigned short)r;
}

__device__ __forceinline__ void async16(const void* g, void* l) {
    __builtin_amdgcn_global_load_lds(
        (const __attribute__((address_space(1))) unsigned int*)g,
        (__attribute__((address_space(3))) unsigned int*)l,
        16, 0, 0);
}

// ---------------------------------------------------------------------------
// dtype detect: bf16 uniform(+-1/32) words have exp field <= 122; fp32 data
// read as u16 words has ~45% of words with exp >= 140. One wave, 4096 words.
// flag: 1 = inputs are fp32, 0 = inputs are bf16.
// ---------------------------------------------------------------------------
__global__ __launch_bounds__(64) void detect_dtype(
    const unsigned short* __restrict__ w, int* __restrict__ flag)
{
    const int t = threadIdx.x;
    int cnt = 0;
    for (int i = t; i < 4096; i += 64) {
        const unsigned e = (w[i] >> 7) & 0xFF;
        cnt += (e >= 140) ? 1 : 0;
    }
#pragma unroll
    for (int off = 32; off; off >>= 1) cnt += __shfl_xor(cnt, off, 64);
    if (t == 0) flag[0] = (cnt >= 8) ? 1 : 0;
}

// ---------------------------------------------------------------------------
// weight convert+transpose: out[c][r] = bf16(in[r][c]); in fp32 or bf16.
// R,C multiples of 32.
// ---------------------------------------------------------------------------
__global__ __launch_bounds__(256) void conv_weight_t(
    const void* __restrict__ in, unsigned short* __restrict__ out,
    int R, int C, const int* __restrict__ flag)
{
    __shared__ unsigned short tile[32][33];
    const int f = *flag;
    const int bc = blockIdx.x * 32;
    const int br = blockIdx.y * 32;
    const int x = threadIdx.x & 31;
    const int y = threadIdx.x >> 5; // 0..7
#pragma unroll
    for (int i = 0; i < 4; i++) {
        const int r = y + i * 8;
        unsigned short v;
        if (f) v = f2bf(((const float*)in)[(size_t)(br + r) * C + bc + x]);
        else   v = ((const unsigned short*)in)[(size_t)(br + r) * C + bc + x];
        tile[r][x] = v;
    }
    __syncthreads();
#pragma unroll
    for (int i = 0; i < 4; i++) {
        const int r = y + i * 8;
        out[(size_t)(bc + r) * R + br + x] = tile[x][r];
    }
}

// flat convert to bf16 (8 elems/thread)
__global__ __launch_bounds__(256) void conv_to_bf16(
    const void* __restrict__ in, unsigned short* __restrict__ out,
    int n, const int* __restrict__ flag)
{
    const int i = (blockIdx.x * 256 + threadIdx.x) * 8;
    if (i >= n) return;
    if (*flag) {
        const float4* p = (const float4*)((const float*)in + i);
        const float4 a = p[0], b = p[1];
        u16x8 o;
        o[0] = f2bf(a.x); o[1] = f2bf(a.y); o[2] = f2bf(a.z); o[3] = f2bf(a.w);
        o[4] = f2bf(b.x); o[5] = f2bf(b.y); o[6] = f2bf(b.z); o[7] = f2bf(b.w);
        *(u16x8*)(out + i) = o;
    } else {
        *(u16x8*)(out + i) = *(const u16x8*)((const unsigned short*)in + i);
    }
}

// bias convert to fp32 (scalar; n <= 1024)
__global__ __launch_bounds__(256) void conv_bias(
    const void* __restrict__ in, float* __restrict__ out,
    int n, const int* __restrict__ flag)
{
    const int i = blockIdx.x * 256 + threadIdx.x;
    if (i >= n) return;
    out[i] = (*flag) ? ((const float*)in)[i]
                     : bf2f(((const unsigned short*)in)[i]);
}

// final output writer: bf16 src -> d_out as fp32 (flag=1) or bf16 (flag=0)
__global__ __launch_bounds__(256) void write_out(
    const unsigned short* __restrict__ src, void* __restrict__ dst,
    int n, const int* __restrict__ flag)
{
    const int i = (blockIdx.x * 256 + threadIdx.x) * 8;
    if (i >= n) return;
    const u16x8 v = *(const u16x8*)(src + i);
    if (*flag) {
        float4 a, b;
        a.x = bf2f(v[0]); a.y = bf2f(v[1]); a.z = bf2f(v[2]); a.w = bf2f(v[3]);
        b.x = bf2f(v[4]); b.y = bf2f(v[5]); b.z = bf2f(v[6]); b.w = bf2f(v[7]);
        float4* p = (float4*)((float*)dst + i);
        p[0] = a; p[1] = b;
    } else {
        *(u16x8*)((unsigned short*)dst + i) = v;
    }
}

// ---------------------------------------------------------------------------
// C[M,N] = act(alpha * A[M,K] @ B[N,K]^T + fbias), bf16 A/B/C, fp32 bias.
// BIAS: 0 = none, 1 = bias[col], 2 = bias[row].  RELU: 0/1.
// M,N multiples of 128, K multiple of 32, 16B-aligned pointers.
// ---------------------------------------------------------------------------
template <int RELU, int BIAS>
__global__ __launch_bounds__(256, 2) void gemm_bt(
    const unsigned short* __restrict__ A, const unsigned short* __restrict__ B,
    const float* __restrict__ bias, unsigned short* __restrict__ C,
    int M, int N, int K, float alpha)
{
    const int bm = blockIdx.y * 128;
    const int bn = blockIdx.x * 128;
    const int t = threadIdx.x;
    const int lane = t & 63;
    const int w = t >> 6;
    const int wr = (w >> 1) * 64;
    const int wc = (w & 1) * 64;

    __shared__ unsigned short sAt[128 * 32];
    __shared__ unsigned short sBt[128 * 32];

    f32x4 acc[4][4];
#pragma unroll
    for (int i = 0; i < 4; i++)
#pragma unroll
        for (int j = 0; j < 4; j++)
            acc[i][j] = (f32x4){0.f, 0.f, 0.f, 0.f};

    // staging: thread t -> lds byte offset t*16 (wave-uniform base + lane*16)
    const int tr = t >> 2;
    const int tc = (t & 3) << 3;
    const unsigned short* ga = A + (size_t)(bm + tr) * K + tc;
    const unsigned short* gb = B + (size_t)(bn + tr) * K + tc;
    unsigned short* la = &sAt[tr * 32 + tc];
    unsigned short* lb = &sBt[tr * 32 + tc];

    const int am = wr + (lane & 15);
    const int bn_ = wc + (lane & 15);
    const int ak = (lane >> 4) * 8;

    for (int k0 = 0; k0 < K; k0 += 32) {
        async16(ga, la);
        async16(ga + (size_t)64 * K, la + 64 * 32);
        async16(gb, lb);
        async16(gb + (size_t)64 * K, lb + 64 * 32);
        ga += 32;
        gb += 32;
        __syncthreads();

        bf16x8 af[4], bfr[4];
#pragma unroll
        for (int i = 0; i < 4; i++)
            af[i] = *(const bf16x8*)&sAt[(am + i * 16) * 32 + ak];
#pragma unroll
        for (int j = 0; j < 4; j++)
            bfr[j] = *(const bf16x8*)&sBt[(bn_ + j * 16) * 32 + ak];
#pragma unroll
        for (int i = 0; i < 4; i++)
#pragma unroll
            for (int j = 0; j < 4; j++)
                acc[i][j] = __builtin_amdgcn_mfma_f32_16x16x32_bf16(
                    af[i], bfr[j], acc[i][j], 0, 0, 0);
        __syncthreads();
    }

    // epilogue: C/D mapping col=lane&15, row=(lane>>4)*4+reg  [m89-verified]
#pragma unroll
    for (int i = 0; i < 4; i++) {
        const int row0 = bm + wr + i * 16 + (lane >> 4) * 4;
#pragma unroll
        for (int j = 0; j < 4; j++) {
            const int col = bn + wc + j * 16 + (lane & 15);
            float bc = 0.f;
            if (BIAS == 1) bc = bias[col];
#pragma unroll
            for (int r = 0; r < 4; r++) {
                float bv = bc;
                if (BIAS == 2) bv = bias[row0 + r];
                float vv = acc[i][j][r] * alpha + bv;
                if (RELU) vv = fmaxf(vv, 0.f);
                C[(size_t)(row0 + r) * N + col] = f2bf(vv);
            }
        }
    }
}

// ---------------------------------------------------------------------------
// In-place row softmax over 2048 bf16 cols; one 256-thread block per row.
// ---------------------------------------------------------------------------
__global__ __launch_bounds__(256) void softmax_rows(unsigned short* S, int n)
{
    const size_t row = blockIdx.x;
    unsigned short* p = S + row * (size_t)n;
    const int t = threadIdx.x;
    const int lane = t & 63;
    const int wave = t >> 6;

    u16x8 v = *(const u16x8*)(p + t * 8);
    float f[8];
    float m = -3.0e38f;
#pragma unroll
    for (int i = 0; i < 8; i++) {
        f[i] = bf2f(v[i]);
        m = fmaxf(m, f[i]);
    }
#pragma unroll
    for (int off = 32; off; off >>= 1) m = fmaxf(m, __shfl_xor(m, off, 64));
    __shared__ float redm[4];
    if (lane == 0) redm[wave] = m;
    __syncthreads();
    m = fmaxf(fmaxf(redm[0], redm[1]), fmaxf(redm[2], redm[3]));

    float e[8];
    float s = 0.f;
#pragma unroll
    for (int i = 0; i < 8; i++) {
        e[i] = __expf(f[i] - m);
        s += e[i];
    }
#pragma unroll
    for (int off = 32; off; off >>= 1) s += __shfl_xor(s, off, 64);
    __shared__ float reds[4];
    if (lane == 0) reds[wave] = s;
    __syncthreads();
    s = reds[0] + reds[1] + reds[2] + reds[3];
    const float inv = 1.0f / s;

    u16x8 o;
#pragma unroll
    for (int i = 0; i < 8; i++) o[i] = f2bf(e[i] * inv);
    *(u16x8*)(p + t * 8) = o;
}

// ---------------------------------------------------------------------------
extern "C" void kernel_launch(void* const* d_in, const int* in_sizes, int n_in,
                              void* d_out, int out_size, void* d_ws, size_t ws_size,
                              hipStream_t stream)
{
    const void* x  = d_in[0];   // [8,2048,1024]
    const void* y  = d_in[1];   // [8,2048,1024]
    const void* W1 = d_in[2];   // [1024,1024]
    const void* b1 = d_in[3];
    const void* W2 = d_in[4];   // [1024,512]
    const void* b2 = d_in[5];
    const void* W3 = d_in[6];   // [512,1024]
    const void* b3 = d_in[7];
    const void* W4 = d_in[8];   // [1024,1024]
    const void* b4 = d_in[9];
    const void* Wq = d_in[10];
    const void* bq = d_in[11];
    const void* Wk = d_in[12];
    const void* bk = d_in[13];
    const void* Wv = d_in[14];
    const void* bv = d_in[15];

    // ws layout
    int* flag = (int*)d_ws;
    float* fb = (float*)((char*)d_ws + 64);            // 7 x 1024 floats
    unsigned short* arena = (unsigned short*)((char*)d_ws + 64 + 7 * 1024 * 4);
    const size_t HM = 512 * 1024;                      // 0.5M elems
    unsigned short* W1t = arena;                       // [1024][1024] 2*HM
    unsigned short* W2t = W1t + 2 * HM;                // [512][1024]  1*HM
    unsigned short* W3t = W2t + 1 * HM;                // [1024][512]  1*HM
    unsigned short* W4t = W3t + 1 * HM;                // [1024][1024] 2*HM
    unsigned short* Wqt = W4t + 2 * HM;
    unsigned short* Wkt = Wqt + 2 * HM;
    unsigned short* Wvt = Wkt + 2 * HM;
    unsigned short* XC  = Wvt + 2 * HM;                // x/y bf16, 32 MiB (16M)
    unsigned short* OUTS= XC + 32 * HM;                // out bf16, 32 MiB (16M)
    unsigned short* VT  = OUTS + 32 * HM;              // [1024][2048], 4 MiB
    unsigned short* SBUF= VT + 4 * HM;                 // [2048][2048], 8 MiB
    // arena total: 44M elems = 88 MiB

    // d_out doubles as bf16 ping/pong (overwritten last by write_out)
    unsigned short* PA = (unsigned short*)d_out;       // bytes [0,32MiB)
    unsigned short* PB = PA + 16 * 1024 * 1024;        // bytes [32,64MiB) if fp32 out

    float* fb1 = fb;
    float* fb2 = fb + 1024;
    float* fb3 = fb + 2048;
    float* fb4 = fb + 3072;
    float* fbq = fb + 4096;
    float* fbk = fb + 5120;
    float* fbv = fb + 6144;

    const dim3 blk(256);
    const int NE = 16 * 1024 * 1024;  // x/y/out element count
    const int Mx = 16384;             // 8*2048 flattened rows

    detect_dtype<<<1, 64, 0, stream>>>((const unsigned short*)W1, flag);

    conv_bias<<<4, blk, 0, stream>>>(b1, fb1, 1024, flag);
    conv_bias<<<2, blk, 0, stream>>>(b2, fb2, 512, flag);
    conv_bias<<<4, blk, 0, stream>>>(b3, fb3, 1024, flag);
    conv_bias<<<4, blk, 0, stream>>>(b4, fb4, 1024, flag);
    conv_bias<<<4, blk, 0, stream>>>(bq, fbq, 1024, flag);
    conv_bias<<<4, blk, 0, stream>>>(bk, fbk, 1024, flag);
    conv_bias<<<4, blk, 0, stream>>>(bv, fbv, 1024, flag);

    conv_weight_t<<<dim3(32, 32), blk, 0, stream>>>(W1, W1t, 1024, 1024, flag);
    conv_weight_t<<<dim3(16, 32), blk, 0, stream>>>(W2, W2t, 1024, 512, flag);
    conv_weight_t<<<dim3(32, 16), blk, 0, stream>>>(W3, W3t, 512, 1024, flag);
    conv_weight_t<<<dim3(32, 32), blk, 0, stream>>>(W4, W4t, 1024, 1024, flag);
    conv_weight_t<<<dim3(32, 32), blk, 0, stream>>>(Wq, Wqt, 1024, 1024, flag);
    conv_weight_t<<<dim3(32, 32), blk, 0, stream>>>(Wk, Wkt, 1024, 1024, flag);
    conv_weight_t<<<dim3(32, 32), blk, 0, stream>>>(Wv, Wvt, 1024, 1024, flag);

    // x -> bf16
    conv_to_bf16<<<8192, blk, 0, stream>>>(x, XC, NE, flag);

    // MLP ping-pong within d_out (ReLU + col bias)
    gemm_bt<1, 1><<<dim3(8, 128), blk, 0, stream>>>(XC, W1t, fb1, PA, Mx, 1024, 1024, 1.f);
    gemm_bt<1, 1><<<dim3(4, 128), blk, 0, stream>>>(PA, W2t, fb2, PB, Mx, 512, 1024, 1.f);
    gemm_bt<1, 1><<<dim3(8, 128), blk, 0, stream>>>(PB, W3t, fb3, PA, Mx, 1024, 512, 1.f);
    gemm_bt<1, 1><<<dim3(8, 128), blk, 0, stream>>>(PA, W4t, fb4, PB, Mx, 1024, 1024, 1.f);

    // q = h4@Wq+bq -> PA ; then y -> bf16 (XC reused, x dead) ; k -> PB
    gemm_bt<0, 1><<<dim3(8, 128), blk, 0, stream>>>(PB, Wqt, fbq, PA, Mx, 1024, 1024, 1.f);
    conv_to_bf16<<<8192, blk, 0, stream>>>(y, XC, NE, flag);
    gemm_bt<0, 1><<<dim3(8, 128), blk, 0, stream>>>(XC, Wkt, fbk, PB, Mx, 1024, 1024, 1.f);

    // attention per batch
    for (int b = 0; b < 8; b++) {
        const size_t off = (size_t)b * 2048 * 1024;
        // vt[d][s] = Wvt[d][:] . y_b[s][:] + bv[d]  (row bias)
        gemm_bt<0, 2><<<dim3(16, 8), blk, 0, stream>>>(Wvt, XC + off, fbv, VT,
                                                       1024, 2048, 1024, 1.f);
        // S_b = q_b @ k_b^T * (1/32)
        gemm_bt<0, 0><<<dim3(16, 16), blk, 0, stream>>>(PA + off, PB + off, nullptr, SBUF,
                                                        2048, 2048, 1024, 0.03125f);
        softmax_rows<<<dim3(2048), blk, 0, stream>>>(SBUF, 2048);
        // out_b = P @ V -> OUTS (ws)
        gemm_bt<0, 0><<<dim3(8, 16), blk, 0, stream>>>(SBUF, VT, nullptr, OUTS + off,
                                                       2048, 1024, 2048, 1.f);
    }

    // OUTS (bf16) -> d_out (fp32 if flag, else bf16)
    write_out<<<8192, blk, 0, stream>>>(OUTS, d_out, NE, flag);
}

// Round 4
// 686.657 us; speedup vs baseline: 1.8444x; 1.8444x over previous
//
#include <hip/hip_runtime.h>
#include <stdint.h>

// CrossAttention, fp32 or bf16 I/O (runtime-detected flag), all-bf16 MFMA
// pipeline. R4: z-batched attention (group size G from ws_size), XCD-aware
// block swizzle for weight GEMMs, PV writes d_out directly when G==8,
// consolidated prologue launches.

typedef __attribute__((ext_vector_type(8))) short bf16x8;
typedef __attribute__((ext_vector_type(4))) float f32x4;
typedef __attribute__((ext_vector_type(8))) unsigned short u16x8;

__device__ __forceinline__ float bf2f(unsigned short u) {
    return __uint_as_float(((unsigned int)u) << 16);
}
__device__ __forceinline__ unsigned short f2bf(float f) {
    unsigned int u = __float_as_uint(f);
    unsigned int r = (u + 0x7fffu + ((u >> 16) & 1u)) >> 16;
    return (unsigned short)r;
}

__device__ __forceinline__ void async16(const void* g, void* l) {
    __builtin_amdgcn_global_load_lds(
        (const __attribute__((address_space(1))) unsigned int*)g,
        (__attribute__((address_space(3))) unsigned int*)l,
        16, 0, 0);
}

// ---------------------------------------------------------------------------
// dtype detect: 1 = fp32 inputs, 0 = bf16 inputs.
// ---------------------------------------------------------------------------
__global__ __launch_bounds__(64) void detect_dtype(
    const unsigned short* __restrict__ w, int* __restrict__ flag)
{
    const int t = threadIdx.x;
    int cnt = 0;
    for (int i = t; i < 4096; i += 64) {
        const unsigned e = (w[i] >> 7) & 0xFF;
        cnt += (e >= 140) ? 1 : 0;
    }
#pragma unroll
    for (int off = 32; off; off >>= 1) cnt += __shfl_xor(cnt, off, 64);
    if (t == 0) flag[0] = (cnt >= 8) ? 1 : 0;
}

// ---------------------------------------------------------------------------
// all 7 biases -> fp32, slots of 1024 floats each (b2 uses 512)
// ---------------------------------------------------------------------------
__global__ __launch_bounds__(256) void conv_bias_all(
    const void* b1, const void* b2, const void* b3, const void* b4,
    const void* bq, const void* bk, const void* bv,
    float* __restrict__ out, const int* __restrict__ flag)
{
    const int i = blockIdx.x * 256 + threadIdx.x;   // [0, 7168)
    const int slot = i >> 10, idx = i & 1023;
    if (slot == 1 && idx >= 512) return;
    const void* src = (slot == 0) ? b1 : (slot == 1) ? b2 : (slot == 2) ? b3 :
                      (slot == 3) ? b4 : (slot == 4) ? bq : (slot == 5) ? bk : bv;
    out[i] = (*flag) ? ((const float*)src)[idx]
                     : bf2f(((const unsigned short*)src)[idx]);
}

// ---------------------------------------------------------------------------
// weight convert+transpose: out[c][r] = bf16(in[r][c]). R,C mult of 32.
// Z variant: 5 x (1024x1024) matrices batched by blockIdx.z.
// ---------------------------------------------------------------------------
__device__ __forceinline__ void wt_body(
    const void* in, unsigned short* out, int R, int C, int f)
{
    __shared__ unsigned short tile[32][33];
    const int bc = blockIdx.x * 32;
    const int br = blockIdx.y * 32;
    const int x = threadIdx.x & 31;
    const int y = threadIdx.x >> 5;
#pragma unroll
    for (int i = 0; i < 4; i++) {
        const int r = y + i * 8;
        unsigned short v;
        if (f) v = f2bf(((const float*)in)[(size_t)(br + r) * C + bc + x]);
        else   v = ((const unsigned short*)in)[(size_t)(br + r) * C + bc + x];
        tile[r][x] = v;
    }
    __syncthreads();
#pragma unroll
    for (int i = 0; i < 4; i++) {
        const int r = y + i * 8;
        out[(size_t)(bc + r) * R + br + x] = tile[x][r];
    }
}

__global__ __launch_bounds__(256) void conv_weight_t(
    const void* in, unsigned short* out, int R, int C, const int* flag)
{
    wt_body(in, out, R, C, *flag);
}

__global__ __launch_bounds__(256) void conv_weight_t5(
    const void* i0, unsigned short* o0, const void* i1, unsigned short* o1,
    const void* i2, unsigned short* o2, const void* i3, unsigned short* o3,
    const void* i4, unsigned short* o4, const int* flag)
{
    const int z = blockIdx.z;
    const void* in = (z == 0) ? i0 : (z == 1) ? i1 : (z == 2) ? i2 : (z == 3) ? i3 : i4;
    unsigned short* out = (z == 0) ? o0 : (z == 1) ? o1 : (z == 2) ? o2 : (z == 3) ? o3 : o4;
    wt_body(in, out, 1024, 1024, *flag);
}

// flat convert to bf16 (8 elems/thread)
__global__ __launch_bounds__(256) void conv_to_bf16(
    const void* __restrict__ in, unsigned short* __restrict__ out,
    int n, const int* __restrict__ flag)
{
    const int i = (blockIdx.x * 256 + threadIdx.x) * 8;
    if (i >= n) return;
    if (*flag) {
        const float4* p = (const float4*)((const float*)in + i);
        const float4 a = p[0], b = p[1];
        u16x8 o;
        o[0] = f2bf(a.x); o[1] = f2bf(a.y); o[2] = f2bf(a.z); o[3] = f2bf(a.w);
        o[4] = f2bf(b.x); o[5] = f2bf(b.y); o[6] = f2bf(b.z); o[7] = f2bf(b.w);
        *(u16x8*)(out + i) = o;
    } else {
        *(u16x8*)(out + i) = *(const u16x8*)((const unsigned short*)in + i);
    }
}

// final writer (fallback path): bf16 src -> d_out fp32/bf16
__global__ __launch_bounds__(256) void write_out(
    const unsigned short* __restrict__ src, void* __restrict__ dst,
    int n, const int* __restrict__ flag)
{
    const int i = (blockIdx.x * 256 + threadIdx.x) * 8;
    if (i >= n) return;
    const u16x8 v = *(const u16x8*)(src + i);
    if (*flag) {
        float4 a, b;
        a.x = bf2f(v[0]); a.y = bf2f(v[1]); a.z = bf2f(v[2]); a.w = bf2f(v[3]);
        b.x = bf2f(v[4]); b.y = bf2f(v[5]); b.z = bf2f(v[6]); b.w = bf2f(v[7]);
        float4* p = (float4*)((float*)dst + i);
        p[0] = a; p[1] = b;
    } else {
        *(u16x8*)((unsigned short*)dst + i) = v;
    }
}

// ---------------------------------------------------------------------------
// C[M,N] = act(alpha * A[M,K] @ B[N,K]^T + fbias), bf16 A/B, fp32 bias.
// BIAS: 0 none, 1 bias[col], 2 bias[row]. RELU 0/1.
// OUTF: 0 = bf16 C; 1 = runtime flag ? fp32 : bf16 (C is void*).
// SWZ: XCD-aware remap (requires gridDim.y % 8 == 0) — use when B is the
//      small/shared operand. Batched via blockIdx.z strides (elements).
// ---------------------------------------------------------------------------
template <int RELU, int BIAS, int OUTF, int SWZ>
__global__ __launch_bounds__(256, 2) void gemm_bt(
    const unsigned short* __restrict__ A, const unsigned short* __restrict__ B,
    const float* __restrict__ bias, void* __restrict__ C,
    int M, int N, int K, float alpha,
    long long sA, long long sB, long long sC, const int* __restrict__ flag)
{
    int bxi = blockIdx.x, byi = blockIdx.y;
    if (SWZ) {
        const int id = byi * gridDim.x + bxi;
        bxi = (id >> 3) % gridDim.x;
        byi = (id >> 3) / gridDim.x * 8 + (id & 7);
    }
    const int z = blockIdx.z;
    A += (size_t)z * (size_t)sA;
    B += (size_t)z * (size_t)sB;
    const size_t cofs = (size_t)z * (size_t)sC;

    const int bm = byi * 128;
    const int bn = bxi * 128;
    const int t = threadIdx.x;
    const int lane = t & 63;
    const int w = t >> 6;
    const int wr = (w >> 1) * 64;
    const int wc = (w & 1) * 64;

    __shared__ unsigned short sAt[128 * 32];
    __shared__ unsigned short sBt[128 * 32];

    f32x4 acc[4][4];
#pragma unroll
    for (int i = 0; i < 4; i++)
#pragma unroll
        for (int j = 0; j < 4; j++)
            acc[i][j] = (f32x4){0.f, 0.f, 0.f, 0.f};

    const int tr = t >> 2;
    const int tc = (t & 3) << 3;
    const unsigned short* ga = A + (size_t)(bm + tr) * K + tc;
    const unsigned short* gb = B + (size_t)(bn + tr) * K + tc;
    unsigned short* la = &sAt[tr * 32 + tc];
    unsigned short* lb = &sBt[tr * 32 + tc];

    const int am = wr + (lane & 15);
    const int bn_ = wc + (lane & 15);
    const int ak = (lane >> 4) * 8;

    for (int k0 = 0; k0 < K; k0 += 32) {
        async16(ga, la);
        async16(ga + (size_t)64 * K, la + 64 * 32);
        async16(gb, lb);
        async16(gb + (size_t)64 * K, lb + 64 * 32);
        ga += 32;
        gb += 32;
        __syncthreads();

        bf16x8 af[4], bfr[4];
#pragma unroll
        for (int i = 0; i < 4; i++)
            af[i] = *(const bf16x8*)&sAt[(am + i * 16) * 32 + ak];
#pragma unroll
        for (int j = 0; j < 4; j++)
            bfr[j] = *(const bf16x8*)&sBt[(bn_ + j * 16) * 32 + ak];
#pragma unroll
        for (int i = 0; i < 4; i++)
#pragma unroll
            for (int j = 0; j < 4; j++)
                acc[i][j] = __builtin_amdgcn_mfma_f32_16x16x32_bf16(
                    af[i], bfr[j], acc[i][j], 0, 0, 0);
        __syncthreads();
    }

    const int fl = OUTF ? *flag : 0;
    // C/D mapping: col=lane&15, row=(lane>>4)*4+reg  [m89-verified]
#pragma unroll
    for (int i = 0; i < 4; i++) {
        const int row0 = bm + wr + i * 16 + (lane >> 4) * 4;
#pragma unroll
        for (int j = 0; j < 4; j++) {
            const int col = bn + wc + j * 16 + (lane & 15);
            float bc = 0.f;
            if (BIAS == 1) bc = bias[col];
#pragma unroll
            for (int r = 0; r < 4; r++) {
                float bv = bc;
                if (BIAS == 2) bv = bias[row0 + r];
                float vv = acc[i][j][r] * alpha + bv;
                if (RELU) vv = fmaxf(vv, 0.f);
                const size_t idx = cofs + (size_t)(row0 + r) * N + col;
                if (OUTF && fl) ((float*)C)[idx] = vv;
                else ((unsigned short*)C)[idx] = f2bf(vv);
            }
        }
    }
}

// ---------------------------------------------------------------------------
// In-place row softmax, 2048 bf16 cols, one 256-thread block per row.
// ---------------------------------------------------------------------------
__global__ __launch_bounds__(256) void softmax_rows(unsigned short* S, int n)
{
    const size_t row = blockIdx.x;
    unsigned short* p = S + row * (size_t)n;
    const int t = threadIdx.x;
    const int lane = t & 63;
    const int wave = t >> 6;

    u16x8 v = *(const u16x8*)(p + t * 8);
    float f[8];
    float m = -3.0e38f;
#pragma unroll
    for (int i = 0; i < 8; i++) {
        f[i] = bf2f(v[i]);
        m = fmaxf(m, f[i]);
    }
#pragma unroll
    for (int off = 32; off; off >>= 1) m = fmaxf(m, __shfl_xor(m, off, 64));
    __shared__ float redm[4];
    if (lane == 0) redm[wave] = m;
    __syncthreads();
    m = fmaxf(fmaxf(redm[0], redm[1]), fmaxf(redm[2], redm[3]));

    float e[8];
    float s = 0.f;
#pragma unroll
    for (int i = 0; i < 8; i++) {
        e[i] = __expf(f[i] - m);
        s += e[i];
    }
#pragma unroll
    for (int off = 32; off; off >>= 1) s += __shfl_xor(s, off, 64);
    __shared__ float reds[4];
    if (lane == 0) reds[wave] = s;
    __syncthreads();
    s = reds[0] + reds[1] + reds[2] + reds[3];
    const float inv = 1.0f / s;

    u16x8 o;
#pragma unroll
    for (int i = 0; i < 8; i++) o[i] = f2bf(e[i] * inv);
    *(u16x8*)(p + t * 8) = o;
}

// ---------------------------------------------------------------------------
extern "C" void kernel_launch(void* const* d_in, const int* in_sizes, int n_in,
                              void* d_out, int out_size, void* d_ws, size_t ws_size,
                              hipStream_t stream)
{
    const void* x  = d_in[0];
    const void* y  = d_in[1];
    const void* W1 = d_in[2];
    const void* b1 = d_in[3];
    const void* W2 = d_in[4];
    const void* b2 = d_in[5];
    const void* W3 = d_in[6];
    const void* b3 = d_in[7];
    const void* W4 = d_in[8];
    const void* b4 = d_in[9];
    const void* Wq = d_in[10];
    const void* bq = d_in[11];
    const void* Wk = d_in[12];
    const void* bk = d_in[13];
    const void* Wv = d_in[14];
    const void* bv = d_in[15];

    int* flag = (int*)d_ws;
    float* fb = (float*)((char*)d_ws + 64);            // 7 slots x 1024 fp32
    unsigned short* arena = (unsigned short*)((char*)d_ws + 64 + 7 * 1024 * 4);
    const size_t baseB = 64 + 7 * 1024 * 4;
    const size_t MEG = 1024ull * 1024ull;              // elems

    // choose attention group size G by ws_size (elems: weights 6M, XC 16M,
    // VT G*2M, SBUF G*4M, OUTS 16M when G<8)
    auto needB = [&](int G, bool direct) -> size_t {
        return baseB + 2ull * ((6 + 16 + (size_t)G * 6 + (direct ? 0 : 16)) * MEG);
    };
    int G; bool direct;
    if (ws_size >= needB(8, true))      { G = 8; direct = true;  }
    else if (ws_size >= needB(4, false)) { G = 4; direct = false; }
    else if (ws_size >= needB(2, false)) { G = 2; direct = false; }
    else                                 { G = 1; direct = false; }

    unsigned short* W1t = arena;                  // [1024][1024]
    unsigned short* W2t = W1t + 1 * MEG;          // [512][1024]
    unsigned short* W3t = W2t + MEG / 2;          // [1024][512]
    unsigned short* W4t = W3t + MEG / 2;          // [1024][1024]
    unsigned short* Wqt = W4t + 1 * MEG;
    unsigned short* Wkt = Wqt + 1 * MEG;
    unsigned short* Wvt = Wkt + 1 * MEG;
    unsigned short* XC  = Wvt + 1 * MEG;          // 16M elems (x/y bf16)
    unsigned short* VT  = XC + 16 * MEG;          // G*2M elems
    unsigned short* SBUF = VT + (size_t)G * 2 * MEG;   // G*4M elems
    unsigned short* OUTS = SBUF + (size_t)G * 4 * MEG; // 16M (fallback only)

    unsigned short* PA = (unsigned short*)d_out;       // q / MLP ping
    unsigned short* PB = PA + 16 * MEG;                // k / MLP pong

    float* fb1 = fb;
    float* fb2 = fb + 1024;
    float* fb3 = fb + 2048;
    float* fb4 = fb + 3072;
    float* fbq = fb + 4096;
    float* fbk = fb + 5120;
    float* fbv = fb + 6144;

    const dim3 blk(256);
    const int NE = 16 * 1024 * 1024;
    const int Mx = 16384;
    const long long Z0 = 0;
    const long long sQK = 2048ll * 1024;   // per-batch q/k/y stride
    const long long sS  = 2048ll * 2048;   // per-batch score stride

    detect_dtype<<<1, 64, 0, stream>>>((const unsigned short*)W1, flag);
    conv_bias_all<<<28, blk, 0, stream>>>(b1, b2, b3, b4, bq, bk, bv, fb, flag);
    conv_weight_t5<<<dim3(32, 32, 5), blk, 0, stream>>>(
        W1, W1t, W4, W4t, Wq, Wqt, Wk, Wkt, Wv, Wvt, flag);
    conv_weight_t<<<dim3(16, 32), blk, 0, stream>>>(W2, W2t, 1024, 512, flag);
    conv_weight_t<<<dim3(32, 16), blk, 0, stream>>>(W3, W3t, 512, 1024, flag);

    conv_to_bf16<<<8192, blk, 0, stream>>>(x, XC, NE, flag);

    // MLP ping-pong in d_out (ReLU + col bias), B = weights -> SWZ on
    gemm_bt<1, 1, 0, 1><<<dim3(8, 128), blk, 0, stream>>>(XC, W1t, fb1, PA, Mx, 1024, 1024, 1.f, Z0, Z0, Z0, flag);
    gemm_bt<1, 1, 0, 1><<<dim3(4, 128), blk, 0, stream>>>(PA, W2t, fb2, PB, Mx, 512, 1024, 1.f, Z0, Z0, Z0, flag);
    gemm_bt<1, 1, 0, 1><<<dim3(8, 128), blk, 0, stream>>>(PB, W3t, fb3, PA, Mx, 1024, 512, 1.f, Z0, Z0, Z0, flag);
    gemm_bt<1, 1, 0, 1><<<dim3(8, 128), blk, 0, stream>>>(PA, W4t, fb4, PB, Mx, 1024, 1024, 1.f, Z0, Z0, Z0, flag);

    // q = h4@Wq+bq -> PA ; y -> XC ; k -> PB
    gemm_bt<0, 1, 0, 1><<<dim3(8, 128), blk, 0, stream>>>(PB, Wqt, fbq, PA, Mx, 1024, 1024, 1.f, Z0, Z0, Z0, flag);
    conv_to_bf16<<<8192, blk, 0, stream>>>(y, XC, NE, flag);
    gemm_bt<0, 1, 0, 1><<<dim3(8, 128), blk, 0, stream>>>(XC, Wkt, fbk, PB, Mx, 1024, 1024, 1.f, Z0, Z0, Z0, flag);

    if (direct) {
        // one pass over all 8 batches; PV writes d_out directly (q/k dead
        // after the scores dispatch completes).
        gemm_bt<0, 2, 0, 0><<<dim3(16, 8, 8), blk, 0, stream>>>(
            Wvt, XC, fbv, VT, 1024, 2048, 1024, 1.f, Z0, sQK, sQK, flag);
        gemm_bt<0, 0, 0, 1><<<dim3(16, 16, 8), blk, 0, stream>>>(
            PA, PB, nullptr, SBUF, 2048, 2048, 1024, 0.03125f, sQK, sQK, sS, flag);
        softmax_rows<<<dim3(8 * 2048), blk, 0, stream>>>(SBUF, 2048);
        gemm_bt<0, 0, 1, 1><<<dim3(8, 16, 8), blk, 0, stream>>>(
            SBUF, VT, nullptr, d_out, 2048, 1024, 2048, 1.f, sS, sQK, sQK, flag);
    } else {
        for (int g = 0; g < 8; g += G) {
            const size_t off = (size_t)g * 2048 * 1024;
            gemm_bt<0, 2, 0, 0><<<dim3(16, 8, G), blk, 0, stream>>>(
                Wvt, XC + off, fbv, VT, 1024, 2048, 1024, 1.f, Z0, sQK, sQK, flag);
            gemm_bt<0, 0, 0, 1><<<dim3(16, 16, G), blk, 0, stream>>>(
                PA + off, PB + off, nullptr, SBUF, 2048, 2048, 1024, 0.03125f, sQK, sQK, sS, flag);
            softmax_rows<<<dim3(G * 2048), blk, 0, stream>>>(SBUF, 2048);
            gemm_bt<0, 0, 0, 1><<<dim3(8, 16, G), blk, 0, stream>>>(
                SBUF, VT, nullptr, OUTS + off, 2048, 1024, 2048, 1.f, sS, sQK, sQK, flag);
        }
        write_out<<<8192, blk, 0, stream>>>(OUTS, d_out, NE, flag);
    }
}

// Round 5
// 665.235 us; speedup vs baseline: 1.9038x; 1.0322x over previous
//
#include <hip/hip_runtime.h>
#include <stdint.h>

// CrossAttention, fp32/bf16 I/O autodetect, all-bf16 MFMA pipeline.
// R5: gemm_bt2 = 128x256 block tile (2 n-tiles/block, acc[4][8]) for the
// large GEMMs (L1,L4,q,k,scores,PV): halves A-refetch and barrier count per
// FLOP. L2,L3,vt + fallback stay on proven gemm_bt. Merged small transposes.

typedef __attribute__((ext_vector_type(8))) short bf16x8;
typedef __attribute__((ext_vector_type(4))) float f32x4;
typedef __attribute__((ext_vector_type(8))) unsigned short u16x8;

__device__ __forceinline__ float bf2f(unsigned short u) {
    return __uint_as_float(((unsigned int)u) << 16);
}
__device__ __forceinline__ unsigned short f2bf(float f) {
    unsigned int u = __float_as_uint(f);
    unsigned int r = (u + 0x7fffu + ((u >> 16) & 1u)) >> 16;
    return (unsigned short)r;
}

__device__ __forceinline__ void async16(const void* g, void* l) {
    __builtin_amdgcn_global_load_lds(
        (const __attribute__((address_space(1))) unsigned int*)g,
        (__attribute__((address_space(3))) unsigned int*)l,
        16, 0, 0);
}

// ---------------------------------------------------------------------------
__global__ __launch_bounds__(64) void detect_dtype(
    const unsigned short* __restrict__ w, int* __restrict__ flag)
{
    const int t = threadIdx.x;
    int cnt = 0;
    for (int i = t; i < 4096; i += 64) {
        const unsigned e = (w[i] >> 7) & 0xFF;
        cnt += (e >= 140) ? 1 : 0;
    }
#pragma unroll
    for (int off = 32; off; off >>= 1) cnt += __shfl_xor(cnt, off, 64);
    if (t == 0) flag[0] = (cnt >= 8) ? 1 : 0;
}

// ---------------------------------------------------------------------------
__global__ __launch_bounds__(256) void conv_bias_all(
    const void* b1, const void* b2, const void* b3, const void* b4,
    const void* bq, const void* bk, const void* bv,
    float* __restrict__ out, const int* __restrict__ flag)
{
    const int i = blockIdx.x * 256 + threadIdx.x;
    const int slot = i >> 10, idx = i & 1023;
    if (slot == 1 && idx >= 512) return;
    const void* src = (slot == 0) ? b1 : (slot == 1) ? b2 : (slot == 2) ? b3 :
                      (slot == 3) ? b4 : (slot == 4) ? bq : (slot == 5) ? bk : bv;
    out[i] = (*flag) ? ((const float*)src)[idx]
                     : bf2f(((const unsigned short*)src)[idx]);
}

// ---------------------------------------------------------------------------
// weight convert+transpose, z-batched over all 7 weights.
// z 0-4: 1024x1024. z=5: W2 (1024x512, bx<16). z=6: W3 (512x1024, by<16).
// ---------------------------------------------------------------------------
__device__ __forceinline__ void wt_body(
    const void* in, unsigned short* out, int R, int C, int f)
{
    __shared__ unsigned short tile[32][33];
    const int bc = blockIdx.x * 32;
    const int br = blockIdx.y * 32;
    const int x = threadIdx.x & 31;
    const int y = threadIdx.x >> 5;
#pragma unroll
    for (int i = 0; i < 4; i++) {
        const int r = y + i * 8;
        unsigned short v;
        if (f) v = f2bf(((const float*)in)[(size_t)(br + r) * C + bc + x]);
        else   v = ((const unsigned short*)in)[(size_t)(br + r) * C + bc + x];
        tile[r][x] = v;
    }
    __syncthreads();
#pragma unroll
    for (int i = 0; i < 4; i++) {
        const int r = y + i * 8;
        out[(size_t)(bc + r) * R + br + x] = tile[x][r];
    }
}

__global__ __launch_bounds__(256) void conv_weight_t7(
    const void* i0, unsigned short* o0, const void* i1, unsigned short* o1,
    const void* i2, unsigned short* o2, const void* i3, unsigned short* o3,
    const void* i4, unsigned short* o4, const void* i5, unsigned short* o5,
    const void* i6, unsigned short* o6, const int* flag)
{
    const int z = blockIdx.z;
    if (z == 5) {                       // W2: 1024x512
        if (blockIdx.x >= 16) return;
        wt_body(i5, o5, 1024, 512, *flag);
        return;
    }
    if (z == 6) {                       // W3: 512x1024
        if (blockIdx.y >= 16) return;
        wt_body(i6, o6, 512, 1024, *flag);
        return;
    }
    const void* in = (z == 0) ? i0 : (z == 1) ? i1 : (z == 2) ? i2 : (z == 3) ? i3 : i4;
    unsigned short* out = (z == 0) ? o0 : (z == 1) ? o1 : (z == 2) ? o2 : (z == 3) ? o3 : o4;
    wt_body(in, out, 1024, 1024, *flag);
}

__global__ __launch_bounds__(256) void conv_to_bf16(
    const void* __restrict__ in, unsigned short* __restrict__ out,
    int n, const int* __restrict__ flag)
{
    const int i = (blockIdx.x * 256 + threadIdx.x) * 8;
    if (i >= n) return;
    if (*flag) {
        const float4* p = (const float4*)((const float*)in + i);
        const float4 a = p[0], b = p[1];
        u16x8 o;
        o[0] = f2bf(a.x); o[1] = f2bf(a.y); o[2] = f2bf(a.z); o[3] = f2bf(a.w);
        o[4] = f2bf(b.x); o[5] = f2bf(b.y); o[6] = f2bf(b.z); o[7] = f2bf(b.w);
        *(u16x8*)(out + i) = o;
    } else {
        *(u16x8*)(out + i) = *(const u16x8*)((const unsigned short*)in + i);
    }
}

__global__ __launch_bounds__(256) void write_out(
    const unsigned short* __restrict__ src, void* __restrict__ dst,
    int n, const int* __restrict__ flag)
{
    const int i = (blockIdx.x * 256 + threadIdx.x) * 8;
    if (i >= n) return;
    const u16x8 v = *(const u16x8*)(src + i);
    if (*flag) {
        float4 a, b;
        a.x = bf2f(v[0]); a.y = bf2f(v[1]); a.z = bf2f(v[2]); a.w = bf2f(v[3]);
        b.x = bf2f(v[4]); b.y = bf2f(v[5]); b.z = bf2f(v[6]); b.w = bf2f(v[7]);
        float4* p = (float4*)((float*)dst + i);
        p[0] = a; p[1] = b;
    } else {
        *(u16x8*)((unsigned short*)dst + i) = v;
    }
}

// ---------------------------------------------------------------------------
// Proven 128x128 GEMM (R3/R4): C = act(alpha*A@B^T + bias).
// ---------------------------------------------------------------------------
template <int RELU, int BIAS, int OUTF, int SWZ>
__global__ __launch_bounds__(256, 2) void gemm_bt(
    const unsigned short* __restrict__ A, const unsigned short* __restrict__ B,
    const float* __restrict__ bias, void* __restrict__ C,
    int M, int N, int K, float alpha,
    long long sA, long long sB, long long sC, const int* __restrict__ flag)
{
    int bxi = blockIdx.x, byi = blockIdx.y;
    if (SWZ) {
        const int id = byi * gridDim.x + bxi;
        bxi = (id >> 3) % gridDim.x;
        byi = (id >> 3) / gridDim.x * 8 + (id & 7);
    }
    const int z = blockIdx.z;
    A += (size_t)z * (size_t)sA;
    B += (size_t)z * (size_t)sB;
    const size_t cofs = (size_t)z * (size_t)sC;

    const int bm = byi * 128;
    const int bn = bxi * 128;
    const int t = threadIdx.x;
    const int lane = t & 63;
    const int w = t >> 6;
    const int wr = (w >> 1) * 64;
    const int wc = (w & 1) * 64;

    __shared__ unsigned short sAt[128 * 32];
    __shared__ unsigned short sBt[128 * 32];

    f32x4 acc[4][4];
#pragma unroll
    for (int i = 0; i < 4; i++)
#pragma unroll
        for (int j = 0; j < 4; j++)
            acc[i][j] = (f32x4){0.f, 0.f, 0.f, 0.f};

    const int tr = t >> 2;
    const int tc = (t & 3) << 3;
    const unsigned short* ga = A + (size_t)(bm + tr) * K + tc;
    const unsigned short* gb = B + (size_t)(bn + tr) * K + tc;
    unsigned short* la = &sAt[tr * 32 + tc];
    unsigned short* lb = &sBt[tr * 32 + tc];

    const int am = wr + (lane & 15);
    const int bn_ = wc + (lane & 15);
    const int ak = (lane >> 4) * 8;

    for (int k0 = 0; k0 < K; k0 += 32) {
        async16(ga, la);
        async16(ga + (size_t)64 * K, la + 64 * 32);
        async16(gb, lb);
        async16(gb + (size_t)64 * K, lb + 64 * 32);
        ga += 32;
        gb += 32;
        __syncthreads();

        bf16x8 af[4], bfr[4];
#pragma unroll
        for (int i = 0; i < 4; i++)
            af[i] = *(const bf16x8*)&sAt[(am + i * 16) * 32 + ak];
#pragma unroll
        for (int j = 0; j < 4; j++)
            bfr[j] = *(const bf16x8*)&sBt[(bn_ + j * 16) * 32 + ak];
#pragma unroll
        for (int i = 0; i < 4; i++)
#pragma unroll
            for (int j = 0; j < 4; j++)
                acc[i][j] = __builtin_amdgcn_mfma_f32_16x16x32_bf16(
                    af[i], bfr[j], acc[i][j], 0, 0, 0);
        __syncthreads();
    }

    const int fl = OUTF ? *flag : 0;
#pragma unroll
    for (int i = 0; i < 4; i++) {
        const int row0 = bm + wr + i * 16 + (lane >> 4) * 4;
#pragma unroll
        for (int j = 0; j < 4; j++) {
            const int col = bn + wc + j * 16 + (lane & 15);
            float bc = 0.f;
            if (BIAS == 1) bc = bias[col];
#pragma unroll
            for (int r = 0; r < 4; r++) {
                float bv = bc;
                if (BIAS == 2) bv = bias[row0 + r];
                float vv = acc[i][j][r] * alpha + bv;
                if (RELU) vv = fmaxf(vv, 0.f);
                const size_t idx = cofs + (size_t)(row0 + r) * N + col;
                if (OUTF && fl) ((float*)C)[idx] = vv;
                else ((unsigned short*)C)[idx] = f2bf(vv);
            }
        }
    }
}

// ---------------------------------------------------------------------------
// R5: 128(m) x 256(n) block tile, 2 n-tiles per block, acc[4][8].
// Per k-step: 6 async16, 12 ds_read_b128, 32 MFMA -> 2x barrier amortization,
// A-refetch halved. Requires N % 256 == 0. ~200 VGPR -> 2 blocks/CU.
// ---------------------------------------------------------------------------
template <int RELU, int BIAS, int OUTF, int SWZ>
__global__ __launch_bounds__(256, 2) void gemm_bt2(
    const unsigned short* __restrict__ A, const unsigned short* __restrict__ B,
    const float* __restrict__ bias, void* __restrict__ C,
    int M, int N, int K, float alpha,
    long long sA, long long sB, long long sC, const int* __restrict__ flag)
{
    int bxi = blockIdx.x, byi = blockIdx.y;
    if (SWZ) {
        const int id = byi * gridDim.x + bxi;
        bxi = (id >> 3) % gridDim.x;
        byi = (id >> 3) / gridDim.x * 8 + (id & 7);
    }
    const int z = blockIdx.z;
    A += (size_t)z * (size_t)sA;
    B += (size_t)z * (size_t)sB;
    const size_t cofs = (size_t)z * (size_t)sC;

    const int bm = byi * 128;
    const int bn = bxi * 256;
    const int t = threadIdx.x;
    const int lane = t & 63;
    const int w = t >> 6;
    const int wr = (w >> 1) * 64;    // wave m-offset: 0/64
    const int wc = (w & 1) * 128;    // wave n-offset: 0/128

    __shared__ unsigned short sAt[128 * 32];
    __shared__ unsigned short sBt[256 * 32];

    f32x4 acc[4][8];
#pragma unroll
    for (int i = 0; i < 4; i++)
#pragma unroll
        for (int j = 0; j < 8; j++)
            acc[i][j] = (f32x4){0.f, 0.f, 0.f, 0.f};

    const int tr = t >> 2;
    const int tc = (t & 3) << 3;
    const unsigned short* ga = A + (size_t)(bm + tr) * K + tc;
    const unsigned short* gb = B + (size_t)(bn + tr) * K + tc;
    unsigned short* la = &sAt[tr * 32 + tc];
    unsigned short* lb = &sBt[tr * 32 + tc];

    const int am = wr + (lane & 15);
    const int bn_ = wc + (lane & 15);
    const int ak = (lane >> 4) * 8;

    for (int k0 = 0; k0 < K; k0 += 32) {
        async16(ga, la);
        async16(ga + (size_t)64 * K, la + 64 * 32);
        async16(gb, lb);
        async16(gb + (size_t)64 * K, lb + 64 * 32);
        async16(gb + (size_t)128 * K, lb + 128 * 32);
        async16(gb + (size_t)192 * K, lb + 192 * 32);
        ga += 32;
        gb += 32;
        __syncthreads();

        bf16x8 af[4], bfr[8];
#pragma unroll
        for (int i = 0; i < 4; i++)
            af[i] = *(const bf16x8*)&sAt[(am + i * 16) * 32 + ak];
#pragma unroll
        for (int j = 0; j < 8; j++)
            bfr[j] = *(const bf16x8*)&sBt[(bn_ + j * 16) * 32 + ak];
#pragma unroll
        for (int i = 0; i < 4; i++)
#pragma unroll
            for (int j = 0; j < 8; j++)
                acc[i][j] = __builtin_amdgcn_mfma_f32_16x16x32_bf16(
                    af[i], bfr[j], acc[i][j], 0, 0, 0);
        __syncthreads();
    }

    const int fl = OUTF ? *flag : 0;
#pragma unroll
    for (int i = 0; i < 4; i++) {
        const int row0 = bm + wr + i * 16 + (lane >> 4) * 4;
#pragma unroll
        for (int j = 0; j < 8; j++) {
            const int col = bn + wc + j * 16 + (lane & 15);
            float bc = 0.f;
            if (BIAS == 1) bc = bias[col];
#pragma unroll
            for (int r = 0; r < 4; r++) {
                float bv = bc;
                if (BIAS == 2) bv = bias[row0 + r];
                float vv = acc[i][j][r] * alpha + bv;
                if (RELU) vv = fmaxf(vv, 0.f);
                const size_t idx = cofs + (size_t)(row0 + r) * N + col;
                if (OUTF && fl) ((float*)C)[idx] = vv;
                else ((unsigned short*)C)[idx] = f2bf(vv);
            }
        }
    }
}

// ---------------------------------------------------------------------------
__global__ __launch_bounds__(256) void softmax_rows(unsigned short* S, int n)
{
    const size_t row = blockIdx.x;
    unsigned short* p = S + row * (size_t)n;
    const int t = threadIdx.x;
    const int lane = t & 63;
    const int wave = t >> 6;

    u16x8 v = *(const u16x8*)(p + t * 8);
    float f[8];
    float m = -3.0e38f;
#pragma unroll
    for (int i = 0; i < 8; i++) {
        f[i] = bf2f(v[i]);
        m = fmaxf(m, f[i]);
    }
#pragma unroll
    for (int off = 32; off; off >>= 1) m = fmaxf(m, __shfl_xor(m, off, 64));
    __shared__ float redm[4];
    if (lane == 0) redm[wave] = m;
    __syncthreads();
    m = fmaxf(fmaxf(redm[0], redm[1]), fmaxf(redm[2], redm[3]));

    float e[8];
    float s = 0.f;
#pragma unroll
    for (int i = 0; i < 8; i++) {
        e[i] = __expf(f[i] - m);
        s += e[i];
    }
#pragma unroll
    for (int off = 32; off; off >>= 1) s += __shfl_xor(s, off, 64);
    __shared__ float reds[4];
    if (lane == 0) reds[wave] = s;
    __syncthreads();
    s = reds[0] + reds[1] + reds[2] + reds[3];
    const float inv = 1.0f / s;

    u16x8 o;
#pragma unroll
    for (int i = 0; i < 8; i++) o[i] = f2bf(e[i] * inv);
    *(u16x8*)(p + t * 8) = o;
}

// ---------------------------------------------------------------------------
extern "C" void kernel_launch(void* const* d_in, const int* in_sizes, int n_in,
                              void* d_out, int out_size, void* d_ws, size_t ws_size,
                              hipStream_t stream)
{
    const void* x  = d_in[0];
    const void* y  = d_in[1];
    const void* W1 = d_in[2];
    const void* b1 = d_in[3];
    const void* W2 = d_in[4];
    const void* b2 = d_in[5];
    const void* W3 = d_in[6];
    const void* b3 = d_in[7];
    const void* W4 = d_in[8];
    const void* b4 = d_in[9];
    const void* Wq = d_in[10];
    const void* bq = d_in[11];
    const void* Wk = d_in[12];
    const void* bk = d_in[13];
    const void* Wv = d_in[14];
    const void* bv = d_in[15];

    int* flag = (int*)d_ws;
    float* fb = (float*)((char*)d_ws + 64);
    unsigned short* arena = (unsigned short*)((char*)d_ws + 64 + 7 * 1024 * 4);
    const size_t baseB = 64 + 7 * 1024 * 4;
    const size_t MEG = 1024ull * 1024ull;

    auto needB = [&](int G, bool direct) -> size_t {
        return baseB + 2ull * ((6 + 16 + (size_t)G * 6 + (direct ? 0 : 16)) * MEG);
    };
    int G; bool direct;
    if (ws_size >= needB(8, true))      { G = 8; direct = true;  }
    else if (ws_size >= needB(4, false)) { G = 4; direct = false; }
    else if (ws_size >= needB(2, false)) { G = 2; direct = false; }
    else                                 { G = 1; direct = false; }

    unsigned short* W1t = arena;
    unsigned short* W2t = W1t + 1 * MEG;
    unsigned short* W3t = W2t + MEG / 2;
    unsigned short* W4t = W3t + MEG / 2;
    unsigned short* Wqt = W4t + 1 * MEG;
    unsigned short* Wkt = Wqt + 1 * MEG;
    unsigned short* Wvt = Wkt + 1 * MEG;
    unsigned short* XC  = Wvt + 1 * MEG;
    unsigned short* VT  = XC + 16 * MEG;
    unsigned short* SBUF = VT + (size_t)G * 2 * MEG;
    unsigned short* OUTS = SBUF + (size_t)G * 4 * MEG;

    unsigned short* PA = (unsigned short*)d_out;
    unsigned short* PB = PA + 16 * MEG;

    float* fb1 = fb;
    float* fb2 = fb + 1024;
    float* fb3 = fb + 2048;
    float* fb4 = fb + 3072;
    float* fbq = fb + 4096;
    float* fbk = fb + 5120;
    float* fbv = fb + 6144;

    const dim3 blk(256);
    const int NE = 16 * 1024 * 1024;
    const int Mx = 16384;
    const long long Z0 = 0;
    const long long sQK = 2048ll * 1024;
    const long long sS  = 2048ll * 2048;

    detect_dtype<<<1, 64, 0, stream>>>((const unsigned short*)W1, flag);
    conv_bias_all<<<28, blk, 0, stream>>>(b1, b2, b3, b4, bq, bk, bv, fb, flag);
    conv_weight_t7<<<dim3(32, 32, 7), blk, 0, stream>>>(
        W1, W1t, W4, W4t, Wq, Wqt, Wk, Wkt, Wv, Wvt, W2, W2t, W3, W3t, flag);

    conv_to_bf16<<<8192, blk, 0, stream>>>(x, XC, NE, flag);

    // MLP: L1/L4 on gemm_bt2 (N=1024), L2/L3 on proven gemm_bt
    gemm_bt2<1, 1, 0, 1><<<dim3(4, 128), blk, 0, stream>>>(XC, W1t, fb1, PA, Mx, 1024, 1024, 1.f, Z0, Z0, Z0, flag);
    gemm_bt <1, 1, 0, 1><<<dim3(4, 128), blk, 0, stream>>>(PA, W2t, fb2, PB, Mx, 512, 1024, 1.f, Z0, Z0, Z0, flag);
    gemm_bt <1, 1, 0, 1><<<dim3(8, 128), blk, 0, stream>>>(PB, W3t, fb3, PA, Mx, 1024, 512, 1.f, Z0, Z0, Z0, flag);
    gemm_bt2<1, 1, 0, 1><<<dim3(4, 128), blk, 0, stream>>>(PA, W4t, fb4, PB, Mx, 1024, 1024, 1.f, Z0, Z0, Z0, flag);

    // q -> PA ; y -> XC ; k -> PB
    gemm_bt2<0, 1, 0, 1><<<dim3(4, 128), blk, 0, stream>>>(PB, Wqt, fbq, PA, Mx, 1024, 1024, 1.f, Z0, Z0, Z0, flag);
    conv_to_bf16<<<8192, blk, 0, stream>>>(y, XC, NE, flag);
    gemm_bt2<0, 1, 0, 1><<<dim3(4, 128), blk, 0, stream>>>(XC, Wkt, fbk, PB, Mx, 1024, 1024, 1.f, Z0, Z0, Z0, flag);

    if (direct) {
        gemm_bt<0, 2, 0, 0><<<dim3(16, 8, 8), blk, 0, stream>>>(
            Wvt, XC, fbv, VT, 1024, 2048, 1024, 1.f, Z0, sQK, sQK, flag);
        gemm_bt2<0, 0, 0, 1><<<dim3(8, 16, 8), blk, 0, stream>>>(
            PA, PB, nullptr, SBUF, 2048, 2048, 1024, 0.03125f, sQK, sQK, sS, flag);
        softmax_rows<<<dim3(8 * 2048), blk, 0, stream>>>(SBUF, 2048);
        gemm_bt2<0, 0, 1, 1><<<dim3(4, 16, 8), blk, 0, stream>>>(
            SBUF, VT, nullptr, d_out, 2048, 1024, 2048, 1.f, sS, sQK, sQK, flag);
    } else {
        for (int g = 0; g < 8; g += G) {
            const size_t off = (size_t)g * 2048 * 1024;
            gemm_bt<0, 2, 0, 0><<<dim3(16, 8, G), blk, 0, stream>>>(
                Wvt, XC + off, fbv, VT, 1024, 2048, 1024, 1.f, Z0, sQK, sQK, flag);
            gemm_bt<0, 0, 0, 1><<<dim3(16, 16, G), blk, 0, stream>>>(
                PA + off, PB + off, nullptr, SBUF, 2048, 2048, 1024, 0.03125f, sQK, sQK, sS, flag);
            softmax_rows<<<dim3(G * 2048), blk, 0, stream>>>(SBUF, 2048);
            gemm_bt<0, 0, 0, 1><<<dim3(8, 16, G), blk, 0, stream>>>(
                SBUF, VT, nullptr, OUTS + off, 2048, 1024, 2048, 1.f, sS, sQK, sQK, flag);
        }
        write_out<<<8192, blk, 0, stream>>>(OUTS, d_out, NE, flag);
    }
}